// Round 14
// baseline (342.154 us; speedup 1.0000x reference)
//
#include <hip/hip_runtime.h>
#include <stdint.h>

#define NDIM 64
#define SCAN_ELEMS 2048   // elements per scan block (256 thr x 8)
#define NCHK 32           // edge chunks
#define NGRP 8            // node-range groups
#define RMAX 6272         // max nodes per group (ceil(50000/8)=6250)

typedef unsigned int uint;
typedef unsigned short ushort;

// round-to-nearest-even fp32 -> bf16 (pair packed into a uint)
__device__ __forceinline__ uint f2bf2(float a, float b) {
  uint ua = __float_as_uint(a);
  uint ub = __float_as_uint(b);
  ua += 0x7fffu + ((ua >> 16) & 1u);
  ub += 0x7fffu + ((ub >> 16) & 1u);
  return (ua >> 16) | (ub & 0xffff0000u);
}
__device__ __forceinline__ float bflo(uint u) { return __uint_as_float(u << 16); }
__device__ __forceinline__ float bfhi(uint u) { return __uint_as_float(u & 0xffff0000u); }

// ---------------- weight transpose (k-major) ----------------
__global__ __launch_bounds__(256) void transpose_kernel(
    const float* __restrict__ fw, const float* __restrict__ rootw,
    const float* __restrict__ lin1, const float* __restrict__ lin2,
    float* __restrict__ fwT, float* __restrict__ wrT,
    float* __restrict__ w1T, float* __restrict__ w2T) {
  int e = blockIdx.x * 256 + threadIdx.x;
  if (e < 16384) {
    int o = e >> 8, k = e & 255;
    fwT[k * 64 + o] = fw[e];
  }
  int e2 = e - 16384;
  if (e2 >= 0 && e2 < 12288) {
    int l = e2 >> 12, r = e2 & 4095;
    int o = r >> 6, k = r & 63;
    size_t t = (size_t)l * 4096 + k * 64 + o;
    wrT[t] = rootw[e2];
    w1T[t] = lin1[e2];
    w2T[t] = lin2[e2];
  }
}

// ---------------- x -> bf16 table ----------------
__global__ __launch_bounds__(256) void convx_kernel(
    const float* __restrict__ x, uint* __restrict__ xb, int n4) {
  int e = blockIdx.x * 256 + threadIdx.x;
  if (e >= n4) return;
  float4 v = ((const float4*)x)[e];
  uint2 o;
  o.x = f2bf2(v.x, v.y);
  o.y = f2bf2(v.z, v.w);
  ((uint2*)xb)[e] = o;
}

// ---------------- CSR build: atomic-free chunked counting sort ----------------
__global__ __launch_bounds__(256) void hist_kernel(
    const int* __restrict__ src, const int* __restrict__ dst,
    int* __restrict__ Hd, int* __restrict__ Hs, int E, int N, int chunk) {
  int c = blockIdx.x, g = blockIdx.y, z = blockIdx.z;
  const int* key = z ? src : dst;
  int* H = z ? Hs : Hd;
  int lo = (int)((long long)N * g / NGRP);
  int hi = (int)((long long)N * (g + 1) / NGRP);
  int range = hi - lo;
  __shared__ int cnt[RMAX];
  for (int i = threadIdx.x; i < range; i += 256) cnt[i] = 0;
  __syncthreads();
  int e0 = c * chunk, e1 = min(E, e0 + chunk);
  for (int e = e0 + (int)threadIdx.x * 4; e < e1; e += 1024) {
    if (e + 4 <= e1) {
      int4 k4 = *(const int4*)(key + e);
      if (k4.x >= lo && k4.x < hi) atomicAdd(&cnt[k4.x - lo], 1);
      if (k4.y >= lo && k4.y < hi) atomicAdd(&cnt[k4.y - lo], 1);
      if (k4.z >= lo && k4.z < hi) atomicAdd(&cnt[k4.z - lo], 1);
      if (k4.w >= lo && k4.w < hi) atomicAdd(&cnt[k4.w - lo], 1);
    } else {
      for (int k = e; k < e1; ++k) {
        int v = key[k];
        if (v >= lo && v < hi) atomicAdd(&cnt[v - lo], 1);
      }
    }
  }
  __syncthreads();
  for (int i = threadIdx.x; i < range; i += 256)
    H[(size_t)c * N + lo + i] = cnt[i];
}

__global__ __launch_bounds__(256) void degsum_kernel(
    const int* __restrict__ Hd, const int* __restrict__ Hs,
    int* __restrict__ deg_d, int* __restrict__ deg_s, int N) {
  int n = blockIdx.x * 256 + threadIdx.x;
  if (n >= N) return;
  int sd = 0, ss = 0;
#pragma unroll
  for (int c = 0; c < NCHK; ++c) {
    sd += Hd[(size_t)c * N + n];
    ss += Hs[(size_t)c * N + n];
  }
  deg_d[n] = sd;
  deg_s[n] = ss;
}

__global__ __launch_bounds__(256) void scan_partial(
    const int* __restrict__ deg_d, const int* __restrict__ deg_s,
    int* __restrict__ bsum, int n, int nb) {
  const int* deg = (blockIdx.y == 0) ? deg_d : deg_s;
  int tid = threadIdx.x;
  int base = blockIdx.x * SCAN_ELEMS;
  int s = 0;
#pragma unroll
  for (int j = 0; j < 8; ++j) {
    int i = base + j * 256 + tid;
    if (i < n) s += deg[i];
  }
#pragma unroll
  for (int off = 1; off < 64; off <<= 1) s += __shfl_xor(s, off);
  __shared__ int ws[4];
  if ((tid & 63) == 0) ws[tid >> 6] = s;
  __syncthreads();
  if (tid == 0) bsum[blockIdx.y * nb + blockIdx.x] = ws[0] + ws[1] + ws[2] + ws[3];
}

__global__ __launch_bounds__(256) void scan_bsum(int* __restrict__ bsum, int nb) {
  __shared__ int sh[256];
  int tid = threadIdx.x;
  for (int h = 0; h < 2; ++h) {
    int v = (tid < nb) ? bsum[h * nb + tid] : 0;
    sh[tid] = v;
    __syncthreads();
    for (int off = 1; off < 256; off <<= 1) {
      int t = (tid >= off) ? sh[tid - off] : 0;
      __syncthreads();
      sh[tid] += t;
      __syncthreads();
    }
    if (tid < nb) bsum[h * nb + tid] = sh[tid] - v;  // exclusive
    __syncthreads();
  }
}

__global__ __launch_bounds__(256) void scan_final(
    const int* __restrict__ deg_d, const int* __restrict__ deg_s,
    const int* __restrict__ bsum,
    int* __restrict__ row_d, int* __restrict__ row_s, int n, int nb) {
  const int* deg = (blockIdx.y == 0) ? deg_d : deg_s;
  int* row = (blockIdx.y == 0) ? row_d : row_s;
  int tid = threadIdx.x;
  int lane = tid & 63;
  int e0 = blockIdx.x * SCAN_ELEMS + tid * 8;
  int v[8];
  int s = 0;
#pragma unroll
  for (int j = 0; j < 8; ++j) {
    int i = e0 + j;
    v[j] = (i < n) ? deg[i] : 0;
    s += v[j];
  }
  int incl = s;
#pragma unroll
  for (int off = 1; off < 64; off <<= 1) {
    int t = __shfl_up(incl, off);
    if (lane >= off) incl += t;
  }
  __shared__ int wsum[4];
  if (lane == 63) wsum[tid >> 6] = incl;
  __syncthreads();
  int woff = 0;
  int w = tid >> 6;
  for (int k = 0; k < 4; ++k)
    if (k < w) woff += wsum[k];
  int run = incl - s + woff + bsum[blockIdx.y * nb + blockIdx.x];
#pragma unroll
  for (int j = 0; j < 8; ++j) {
    int i = e0 + j;
    if (i <= n) row[i] = run;
    run += v[j];
  }
}

__global__ __launch_bounds__(256) void cursor_kernel(
    int* __restrict__ Hd, int* __restrict__ Hs,
    const int* __restrict__ row_d, const int* __restrict__ row_s, int N) {
  int n = blockIdx.x * 256 + threadIdx.x;
  if (n >= N) return;
  int rd = row_d[n], rs = row_s[n];
#pragma unroll
  for (int c = 0; c < NCHK; ++c) {
    int t = Hd[(size_t)c * N + n]; Hd[(size_t)c * N + n] = rd; rd += t;
    t = Hs[(size_t)c * N + n];     Hs[(size_t)c * N + n] = rs; rs += t;
  }
}

__global__ __launch_bounds__(256) void scatter_kernel(
    const int* __restrict__ src, const int* __restrict__ dst,
    const int* __restrict__ Hd, const int* __restrict__ Hs,
    int* __restrict__ col_d, int* __restrict__ col_s, int E, int N, int chunk) {
  int g = blockIdx.x, c = blockIdx.y, z = blockIdx.z;
  const int* key = z ? src : dst;
  const int* val = z ? dst : src;
  const int* H = z ? Hs : Hd;
  int* colp = z ? col_s : col_d;
  int lo = (int)((long long)N * g / NGRP);
  int hi = (int)((long long)N * (g + 1) / NGRP);
  int range = hi - lo;
  __shared__ int cur[RMAX];
  for (int i = threadIdx.x; i < range; i += 256)
    cur[i] = H[(size_t)c * N + lo + i];
  __syncthreads();
  int e0 = c * chunk, e1 = min(E, e0 + chunk);
  for (int e = e0 + (int)threadIdx.x * 4; e < e1; e += 1024) {
    if (e + 4 <= e1) {
      int4 k4 = *(const int4*)(key + e);
      int4 v4 = *(const int4*)(val + e);
      if (k4.x >= lo && k4.x < hi) { int p = atomicAdd(&cur[k4.x - lo], 1); colp[p] = v4.x; }
      if (k4.y >= lo && k4.y < hi) { int p = atomicAdd(&cur[k4.y - lo], 1); colp[p] = v4.y; }
      if (k4.z >= lo && k4.z < hi) { int p = atomicAdd(&cur[k4.z - lo], 1); colp[p] = v4.z; }
      if (k4.w >= lo && k4.w < hi) { int p = atomicAdd(&cur[k4.w - lo], 1); colp[p] = v4.w; }
    } else {
      for (int k = e; k < e1; ++k) {
        int kk = key[k], vv = val[k];
        if (kk >= lo && kk < hi) { int p = atomicAdd(&cur[kk - lo], 1); colp[p] = vv; }
      }
    }
  }
}

// ---------------- aggregation: XCD-feature-split, 8 nodes/wave, no reduce ----------
// 1D grid; bit0 of blockIdx.x = feature half. XCD id = linear%8 (measured),
// so even XCDs touch only features [0,32), odd only [32,64): each XCD's
// active sub-table is 3.2 MB < 4 MB L2 -> gather rows become L2 hits.
// Lane: g=lane>>3 node slot, fl=lane&7 -> 4 features (uint2 = 64B line/node).
// Degree divergence branch-free: 0/1 FMA weight, clamped col index.

__global__ __launch_bounds__(256) void aggx_kernel(
    const ushort* __restrict__ hB,
    const int* __restrict__ row_d, const int* __restrict__ col_d, ushort* __restrict__ g1,
    const int* __restrict__ row_s, const int* __restrict__ col_s, ushort* __restrict__ g2,
    int N, int E) {
  int b = blockIdx.x;
  int fh = b & 1;
  int rest = b >> 1;
  int dir = rest & 1;
  int wvblk = rest >> 1;
  const int* row = dir ? row_s : row_d;
  const int* col = dir ? col_s : col_d;
  ushort* outp = dir ? g2 : g1;
  int lane = threadIdx.x & 63;
  int g = lane >> 3;
  int fl = lane & 7;
  int node = (wvblk * 4 + (threadIdx.x >> 6)) * 8 + g;
  int nc = min(node, N - 1);
  int s0 = row[nc], s1 = row[nc + 1];
  int d = s1 - s0;
  int dmax = d;
  dmax = max(dmax, __shfl_xor(dmax, 8));
  dmax = max(dmax, __shfl_xor(dmax, 16));
  dmax = max(dmax, __shfl_xor(dmax, 32));
  const ushort* tab = hB + fh * 32 + fl * 4;
  float a0 = 0.f, a1 = 0.f, a2 = 0.f, a3 = 0.f;
  float b0 = 0.f, b1 = 0.f, b2 = 0.f, b3 = 0.f;
  int i = 0;
  for (; i + 2 <= dmax; i += 2) {
    int p0 = s0 + i, p1 = p0 + 1;
    float w0 = p0 < s1 ? 1.f : 0.f;
    float w1 = p1 < s1 ? 1.f : 0.f;
    int n0 = col[min(p0, E - 1)];
    int n1 = col[min(p1, E - 1)];
    uint2 u0 = *(const uint2*)(tab + (size_t)n0 * 64);
    uint2 u1 = *(const uint2*)(tab + (size_t)n1 * 64);
    a0 += w0 * bflo(u0.x); a1 += w0 * bfhi(u0.x);
    a2 += w0 * bflo(u0.y); a3 += w0 * bfhi(u0.y);
    b0 += w1 * bflo(u1.x); b1 += w1 * bfhi(u1.x);
    b2 += w1 * bflo(u1.y); b3 += w1 * bfhi(u1.y);
  }
  if (i < dmax) {
    int p = s0 + i;
    float w = p < s1 ? 1.f : 0.f;
    int n = col[min(p, E - 1)];
    uint2 u = *(const uint2*)(tab + (size_t)n * 64);
    a0 += w * bflo(u.x); a1 += w * bfhi(u.x);
    a2 += w * bflo(u.y); a3 += w * bfhi(u.y);
  }
  a0 += b0; a1 += b1; a2 += b2; a3 += b3;
  float inv = d > 0 ? 1.f / (float)d : 0.f;
  if (node < N) {
    uint2 o;
    o.x = f2bf2(a0 * inv, a1 * inv);
    o.y = f2bf2(a2 * inv, a3 * inv);
    *(uint2*)(outp + (size_t)node * NDIM + fh * 32 + fl * 4) = o;
  }
}

// ---------------- combine: 128-node bf16 LDS tile, 2 nodes/lane, wave=16 outputs --------

__global__ __launch_bounds__(256, 3) void combine_kernel(
    const ushort* __restrict__ hBin, const ushort* __restrict__ g1b,
    const ushort* __restrict__ g2b, const float* __restrict__ wrT,
    const float* __restrict__ w1T, const float* __restrict__ w2T,
    const float* __restrict__ bias, ushort* __restrict__ hbout, int N) {
  __shared__ uint Ht[128][33];
  __shared__ uint G1t[128][33];
  __shared__ uint G2t[128][33];
  int tid = threadIdx.x;
  int n0 = blockIdx.x * 128;
  {
    int r = tid >> 1, hf = tid & 1;
    int nc = min(n0 + r, N - 1);
    const uint4* ph = (const uint4*)(hBin + (size_t)nc * 64);
    const uint4* p1 = (const uint4*)(g1b + (size_t)nc * 64);
    const uint4* p2 = (const uint4*)(g2b + (size_t)nc * 64);
#pragma unroll
    for (int i = 0; i < 4; ++i) {
      int q = hf * 4 + i;
      uint4 a = ph[q], b = p1[q], c = p2[q];
      int base = q * 4;
      Ht[r][base+0]=a.x;  Ht[r][base+1]=a.y;  Ht[r][base+2]=a.z;  Ht[r][base+3]=a.w;
      G1t[r][base+0]=b.x; G1t[r][base+1]=b.y; G1t[r][base+2]=b.z; G1t[r][base+3]=b.w;
      G2t[r][base+0]=c.x; G2t[r][base+1]=c.y; G2t[r][base+2]=c.z; G2t[r][base+3]=c.w;
    }
  }
  __syncthreads();
  int w = __builtin_amdgcn_readfirstlane(tid >> 6);
  int lane = tid & 63;
  int ob = w * 16;
  float aa[16], ab[16];
#pragma unroll
  for (int o = 0; o < 16; ++o) { float bv = bias[ob + o]; aa[o] = bv; ab[o] = bv; }
  for (int kp = 0; kp < 32; ++kp) {
    uint hua = Ht[lane][kp],  hub = Ht[lane + 64][kp];
    uint gua = G1t[lane][kp], gub = G1t[lane + 64][kp];
    uint fua = G2t[lane][kp], fub = G2t[lane + 64][kp];
    float ha0 = bflo(hua), ha1 = bfhi(hua), hb0 = bflo(hub), hb1 = bfhi(hub);
    float ga0 = bflo(gua), ga1 = bfhi(gua), gb0 = bflo(gub), gb1 = bfhi(gub);
    float fa0 = bflo(fua), fa1 = bfhi(fua), fb0 = bflo(fub), fb1 = bfhi(fub);
    const float4* pa0 = (const float4*)(wrT + (2 * kp) * 64 + ob);
    const float4* pa1 = (const float4*)(wrT + (2 * kp + 1) * 64 + ob);
    const float4* pb0 = (const float4*)(w1T + (2 * kp) * 64 + ob);
    const float4* pb1 = (const float4*)(w1T + (2 * kp + 1) * 64 + ob);
    const float4* pc0 = (const float4*)(w2T + (2 * kp) * 64 + ob);
    const float4* pc1 = (const float4*)(w2T + (2 * kp + 1) * 64 + ob);
#pragma unroll
    for (int j = 0; j < 4; ++j) {
      float4 A0 = pa0[j], A1 = pa1[j];
      float4 B0 = pb0[j], B1 = pb1[j];
      float4 C0 = pc0[j], C1 = pc1[j];
      aa[4*j+0] += ha0*A0.x + ha1*A1.x + ga0*B0.x + ga1*B1.x + fa0*C0.x + fa1*C1.x;
      aa[4*j+1] += ha0*A0.y + ha1*A1.y + ga0*B0.y + ga1*B1.y + fa0*C0.y + fa1*C1.y;
      aa[4*j+2] += ha0*A0.z + ha1*A1.z + ga0*B0.z + ga1*B1.z + fa0*C0.z + fa1*C1.z;
      aa[4*j+3] += ha0*A0.w + ha1*A1.w + ga0*B0.w + ga1*B1.w + fa0*C0.w + fa1*C1.w;
      ab[4*j+0] += hb0*A0.x + hb1*A1.x + gb0*B0.x + gb1*B1.x + fb0*C0.x + fb1*C1.x;
      ab[4*j+1] += hb0*A0.y + hb1*A1.y + gb0*B0.y + gb1*B1.y + fb0*C0.y + fb1*C1.y;
      ab[4*j+2] += hb0*A0.z + hb1*A1.z + gb0*B0.z + gb1*B1.z + fb0*C0.z + fb1*C1.z;
      ab[4*j+3] += hb0*A0.w + hb1*A1.w + gb0*B0.w + gb1*B1.w + fb0*C0.w + fb1*C1.w;
    }
  }
  int na = n0 + lane, nb = n0 + 64 + lane;
  if (na < N) {
    uint4 u0, u1;
    u0.x = f2bf2(fmaxf(aa[0],0.f),  fmaxf(aa[1],0.f));
    u0.y = f2bf2(fmaxf(aa[2],0.f),  fmaxf(aa[3],0.f));
    u0.z = f2bf2(fmaxf(aa[4],0.f),  fmaxf(aa[5],0.f));
    u0.w = f2bf2(fmaxf(aa[6],0.f),  fmaxf(aa[7],0.f));
    u1.x = f2bf2(fmaxf(aa[8],0.f),  fmaxf(aa[9],0.f));
    u1.y = f2bf2(fmaxf(aa[10],0.f), fmaxf(aa[11],0.f));
    u1.z = f2bf2(fmaxf(aa[12],0.f), fmaxf(aa[13],0.f));
    u1.w = f2bf2(fmaxf(aa[14],0.f), fmaxf(aa[15],0.f));
    uint4* op = (uint4*)(hbout + (size_t)na * NDIM + ob);
    op[0] = u0; op[1] = u1;
  }
  if (nb < N) {
    uint4 u0, u1;
    u0.x = f2bf2(fmaxf(ab[0],0.f),  fmaxf(ab[1],0.f));
    u0.y = f2bf2(fmaxf(ab[2],0.f),  fmaxf(ab[3],0.f));
    u0.z = f2bf2(fmaxf(ab[4],0.f),  fmaxf(ab[5],0.f));
    u0.w = f2bf2(fmaxf(ab[6],0.f),  fmaxf(ab[7],0.f));
    u1.x = f2bf2(fmaxf(ab[8],0.f),  fmaxf(ab[9],0.f));
    u1.y = f2bf2(fmaxf(ab[10],0.f), fmaxf(ab[11],0.f));
    u1.z = f2bf2(fmaxf(ab[12],0.f), fmaxf(ab[13],0.f));
    u1.w = f2bf2(fmaxf(ab[14],0.f), fmaxf(ab[15],0.f));
    uint4* op = (uint4*)(hbout + (size_t)nb * NDIM + ob);
    op[0] = u0; op[1] = u1;
  }
}

// ---------------- final: 128-node bf16 LDS tiles (4 bufs), 2 nodes/lane ----------------

__global__ __launch_bounds__(256, 2) void final_kernel(
    const ushort* __restrict__ xB, const ushort* __restrict__ h1B,
    const ushort* __restrict__ h2B, const ushort* __restrict__ h3B,
    const float* __restrict__ fwT, const float* __restrict__ fb,
    float* __restrict__ outp, int N) {
  __shared__ uint Ft[4][128][33];
  int tid = threadIdx.x;
  int n0 = blockIdx.x * 128;
  {
    int r = tid >> 1, hf = tid & 1;
    int nc = min(n0 + r, N - 1);
    const ushort* bufs[4] = {xB, h1B, h2B, h3B};
#pragma unroll
    for (int b = 0; b < 4; ++b) {
      const uint4* ip = (const uint4*)(bufs[b] + (size_t)nc * 64);
#pragma unroll
      for (int i = 0; i < 4; ++i) {
        int q = hf * 4 + i;
        uint4 v = ip[q];
        int base = q * 4;
        Ft[b][r][base+0]=v.x; Ft[b][r][base+1]=v.y;
        Ft[b][r][base+2]=v.z; Ft[b][r][base+3]=v.w;
      }
    }
  }
  __syncthreads();
  int w = __builtin_amdgcn_readfirstlane(tid >> 6);
  int lane = tid & 63;
  int ob = w * 16;
  float aa[16], ab[16];
#pragma unroll
  for (int o = 0; o < 16; ++o) { float bv = fb[ob + o]; aa[o] = bv; ab[o] = bv; }
  for (int kp = 0; kp < 128; ++kp) {
    int buf = kp >> 5, kk = kp & 31;
    uint ua = Ft[buf][lane][kk], ub = Ft[buf][lane + 64][kk];
    float a0 = bflo(ua), a1 = bfhi(ua), b0 = bflo(ub), b1 = bfhi(ub);
    const float4* p0 = (const float4*)(fwT + (2 * kp) * 64 + ob);
    const float4* p1 = (const float4*)(fwT + (2 * kp + 1) * 64 + ob);
#pragma unroll
    for (int j = 0; j < 4; ++j) {
      float4 W0 = p0[j], W1 = p1[j];
      aa[4*j+0] += a0*W0.x + a1*W1.x;
      aa[4*j+1] += a0*W0.y + a1*W1.y;
      aa[4*j+2] += a0*W0.z + a1*W1.z;
      aa[4*j+3] += a0*W0.w + a1*W1.w;
      ab[4*j+0] += b0*W0.x + b1*W1.x;
      ab[4*j+1] += b0*W0.y + b1*W1.y;
      ab[4*j+2] += b0*W0.z + b1*W1.z;
      ab[4*j+3] += b0*W0.w + b1*W1.w;
    }
  }
  int na = n0 + lane, nb = n0 + 64 + lane;
  if (na < N) {
    float4* op = (float4*)(outp + (size_t)na * NDIM + ob);
#pragma unroll
    for (int j = 0; j < 4; ++j) {
      float4 v; v.x = aa[4*j+0]; v.y = aa[4*j+1]; v.z = aa[4*j+2]; v.w = aa[4*j+3];
      op[j] = v;
    }
  }
  if (nb < N) {
    float4* op = (float4*)(outp + (size_t)nb * NDIM + ob);
#pragma unroll
    for (int j = 0; j < 4; ++j) {
      float4 v; v.x = ab[4*j+0]; v.y = ab[4*j+1]; v.z = ab[4*j+2]; v.w = ab[4*j+3];
      op[j] = v;
    }
  }
}

// ---------------- launch ----------------

extern "C" void kernel_launch(void* const* d_in, const int* in_sizes, int n_in,
                              void* d_out, int out_size, void* d_ws, size_t ws_size,
                              hipStream_t stream) {
  const float* x     = (const float*)d_in[0];
  const int*   ei    = (const int*)d_in[1];
  const float* lin1  = (const float*)d_in[2];
  const float* lin2  = (const float*)d_in[3];
  const float* rootw = (const float*)d_in[4];
  const float* rootb = (const float*)d_in[5];
  const float* fw    = (const float*)d_in[6];
  const float* fb    = (const float*)d_in[7];
  float* out = (float*)d_out;

  int N = in_sizes[0] / NDIM;
  int E = in_sizes[1] / 2;
  const int* src = ei;
  const int* dst = ei + E;

  int* ip = (int*)d_ws;
  int* Hd    = ip; ip += (size_t)NCHK * N;
  int* Hs    = ip; ip += (size_t)NCHK * N;
  int* deg_d = ip; ip += N;
  int* deg_s = ip; ip += N;
  int* row_d = ip; ip += N + 1;
  int* row_s = ip; ip += N + 1;
  int* bsum  = ip; ip += 256;
  int* col_d = ip; ip += E;
  int* col_s = ip; ip += E;
  uintptr_t fbase = (((uintptr_t)ip) + 255) & ~(uintptr_t)255;
  float* fwT = (float*)fbase;
  float* wrT = fwT + 16384;
  float* w1T = wrT + 12288;
  float* w2T = w1T + 12288;
  ushort* hB0 = (ushort*)(w2T + 12288);
  ushort* hB1 = hB0 + (size_t)N * NDIM;
  ushort* hB2 = hB1 + (size_t)N * NDIM;
  ushort* hB3 = hB2 + (size_t)N * NDIM;
  ushort* g1b = hB3 + (size_t)N * NDIM;
  ushort* g2b = g1b + (size_t)N * NDIM;

  int chunk = (E + NCHK - 1) / NCHK;
  int nb = (N + SCAN_ELEMS - 1) / SCAN_ELEMS;
  int nblk = (N + 255) / 256;

  transpose_kernel<<<112, 256, 0, stream>>>(fw, rootw, lin1, lin2, fwT, wrT, w1T, w2T);
  convx_kernel<<<(N * 16 + 255) / 256, 256, 0, stream>>>(x, (uint*)hB0, N * 16);
  hist_kernel<<<dim3(NCHK, NGRP, 2), 256, 0, stream>>>(src, dst, Hd, Hs, E, N, chunk);
  degsum_kernel<<<nblk, 256, 0, stream>>>(Hd, Hs, deg_d, deg_s, N);
  scan_partial<<<dim3(nb, 2), 256, 0, stream>>>(deg_d, deg_s, bsum, N, nb);
  scan_bsum<<<1, 256, 0, stream>>>(bsum, nb);
  scan_final<<<dim3(nb, 2), 256, 0, stream>>>(deg_d, deg_s, bsum, row_d, row_s, N, nb);
  cursor_kernel<<<nblk, 256, 0, stream>>>(Hd, Hs, row_d, row_s, N);
  scatter_kernel<<<dim3(NGRP, NCHK, 2), 256, 0, stream>>>(src, dst, Hd, Hs,
                                                          col_d, col_s, E, N, chunk);

  int nwb = (N + 31) / 32;          // node blocks (4 waves x 8 nodes)
  int axgrid = nwb * 4;             // x (fh bit0, dir bit1, node-block rest)
  int tgrid = (N + 127) / 128;
  ushort* hBufs[4] = {hB0, hB1, hB2, hB3};
  for (int l = 0; l < 3; ++l) {
    aggx_kernel<<<axgrid, 256, 0, stream>>>(hBufs[l], row_d, col_d, g1b,
                                            row_s, col_s, g2b, N, E);
    combine_kernel<<<tgrid, 256, 0, stream>>>(hBufs[l], g1b, g2b,
                                              wrT + (size_t)l * 4096,
                                              w1T + (size_t)l * 4096,
                                              w2T + (size_t)l * 4096,
                                              rootb + (size_t)l * 64,
                                              hBufs[l + 1], N);
  }
  final_kernel<<<tgrid, 256, 0, stream>>>(hB0, hB1, hB2, hB3, fwT, fb, out, N);
}

// Round 15
// 306.858 us; speedup vs baseline: 1.1150x; 1.1150x over previous
//
#include <hip/hip_runtime.h>
#include <stdint.h>

#define NDIM 64
#define HDIM 32           // half-table row (bf16) -> 64B, no shared L2 lines
#define SCAN_ELEMS 2048
#define NCHK 32           // edge chunks
#define NGRP 8            // node-range groups
#define RMAX 6272         // ceil(50000/8)=6250

typedef unsigned int uint;
typedef unsigned short ushort;

__device__ __forceinline__ uint f2bf2(float a, float b) {
  uint ua = __float_as_uint(a);
  uint ub = __float_as_uint(b);
  ua += 0x7fffu + ((ua >> 16) & 1u);
  ub += 0x7fffu + ((ub >> 16) & 1u);
  return (ua >> 16) | (ub & 0xffff0000u);
}
__device__ __forceinline__ float bflo(uint u) { return __uint_as_float(u << 16); }
__device__ __forceinline__ float bfhi(uint u) { return __uint_as_float(u & 0xffff0000u); }

// ---------------- weight transpose (k-major) ----------------
__global__ __launch_bounds__(256) void transpose_kernel(
    const float* __restrict__ fw, const float* __restrict__ rootw,
    const float* __restrict__ lin1, const float* __restrict__ lin2,
    float* __restrict__ fwT, float* __restrict__ wrT,
    float* __restrict__ w1T, float* __restrict__ w2T) {
  int e = blockIdx.x * 256 + threadIdx.x;
  if (e < 16384) {
    int o = e >> 8, k = e & 255;
    fwT[k * 64 + o] = fw[e];
  }
  int e2 = e - 16384;
  if (e2 >= 0 && e2 < 12288) {
    int l = e2 >> 12, r = e2 & 4095;
    int o = r >> 6, k = r & 63;
    size_t t = (size_t)l * 4096 + k * 64 + o;
    wrT[t] = rootw[e2];
    w1T[t] = lin1[e2];
    w2T[t] = lin2[e2];
  }
}

// ---------------- x -> split bf16 tables ----------------
__global__ __launch_bounds__(256) void convx_kernel(
    const float* __restrict__ x, ushort* __restrict__ xLo,
    ushort* __restrict__ xHi, int n4) {
  int e = blockIdx.x * 256 + threadIdx.x;
  if (e >= n4) return;                 // e indexes float4 groups (16 per node)
  int n = e >> 4, q = e & 15;
  float4 v = ((const float4*)x)[e];
  uint2 o;
  o.x = f2bf2(v.x, v.y);
  o.y = f2bf2(v.z, v.w);
  ushort* tbl = (q < 8) ? xLo : xHi;
  *(uint2*)(tbl + (size_t)n * HDIM + (q & 7) * 4) = o;
}

// ---------------- CSR build: atomic-free chunked counting sort ----------------
__global__ __launch_bounds__(256) void hist_kernel(
    const int* __restrict__ src, const int* __restrict__ dst,
    int* __restrict__ Hd, int* __restrict__ Hs, int E, int N, int chunk) {
  int c = blockIdx.x, g = blockIdx.y, z = blockIdx.z;
  const int* key = z ? src : dst;
  int* H = z ? Hs : Hd;
  int lo = (int)((long long)N * g / NGRP);
  int hi = (int)((long long)N * (g + 1) / NGRP);
  int range = hi - lo;
  __shared__ int cnt[RMAX];
  for (int i = threadIdx.x; i < range; i += 256) cnt[i] = 0;
  __syncthreads();
  int e0 = c * chunk, e1 = min(E, e0 + chunk);
  for (int e = e0 + (int)threadIdx.x * 4; e < e1; e += 1024) {
    if (e + 4 <= e1) {
      int4 k4 = *(const int4*)(key + e);
      if (k4.x >= lo && k4.x < hi) atomicAdd(&cnt[k4.x - lo], 1);
      if (k4.y >= lo && k4.y < hi) atomicAdd(&cnt[k4.y - lo], 1);
      if (k4.z >= lo && k4.z < hi) atomicAdd(&cnt[k4.z - lo], 1);
      if (k4.w >= lo && k4.w < hi) atomicAdd(&cnt[k4.w - lo], 1);
    } else {
      for (int k = e; k < e1; ++k) {
        int v = key[k];
        if (v >= lo && v < hi) atomicAdd(&cnt[v - lo], 1);
      }
    }
  }
  __syncthreads();
  for (int i = threadIdx.x; i < range; i += 256)
    H[(size_t)c * N + lo + i] = cnt[i];
}

__global__ __launch_bounds__(256) void degsum_kernel(
    const int* __restrict__ Hd, const int* __restrict__ Hs,
    int* __restrict__ deg_d, int* __restrict__ deg_s, int N) {
  int n = blockIdx.x * 256 + threadIdx.x;
  if (n >= N) return;
  int sd = 0, ss = 0;
#pragma unroll
  for (int c = 0; c < NCHK; ++c) {
    sd += Hd[(size_t)c * N + n];
    ss += Hs[(size_t)c * N + n];
  }
  deg_d[n] = sd;
  deg_s[n] = ss;
}

__global__ __launch_bounds__(256) void scan_partial(
    const int* __restrict__ deg_d, const int* __restrict__ deg_s,
    int* __restrict__ bsum, int n, int nb) {
  const int* deg = (blockIdx.y == 0) ? deg_d : deg_s;
  int tid = threadIdx.x;
  int base = blockIdx.x * SCAN_ELEMS;
  int s = 0;
#pragma unroll
  for (int j = 0; j < 8; ++j) {
    int i = base + j * 256 + tid;
    if (i < n) s += deg[i];
  }
#pragma unroll
  for (int off = 1; off < 64; off <<= 1) s += __shfl_xor(s, off);
  __shared__ int ws[4];
  if ((tid & 63) == 0) ws[tid >> 6] = s;
  __syncthreads();
  if (tid == 0) bsum[blockIdx.y * nb + blockIdx.x] = ws[0] + ws[1] + ws[2] + ws[3];
}

__global__ __launch_bounds__(256) void scan_bsum(int* __restrict__ bsum, int nb) {
  __shared__ int sh[256];
  int tid = threadIdx.x;
  for (int h = 0; h < 2; ++h) {
    int v = (tid < nb) ? bsum[h * nb + tid] : 0;
    sh[tid] = v;
    __syncthreads();
    for (int off = 1; off < 256; off <<= 1) {
      int t = (tid >= off) ? sh[tid - off] : 0;
      __syncthreads();
      sh[tid] += t;
      __syncthreads();
    }
    if (tid < nb) bsum[h * nb + tid] = sh[tid] - v;
    __syncthreads();
  }
}

__global__ __launch_bounds__(256) void scan_final(
    const int* __restrict__ deg_d, const int* __restrict__ deg_s,
    const int* __restrict__ bsum,
    int* __restrict__ row_d, int* __restrict__ row_s, int n, int nb) {
  const int* deg = (blockIdx.y == 0) ? deg_d : deg_s;
  int* row = (blockIdx.y == 0) ? row_d : row_s;
  int tid = threadIdx.x;
  int lane = tid & 63;
  int e0 = blockIdx.x * SCAN_ELEMS + tid * 8;
  int v[8];
  int s = 0;
#pragma unroll
  for (int j = 0; j < 8; ++j) {
    int i = e0 + j;
    v[j] = (i < n) ? deg[i] : 0;
    s += v[j];
  }
  int incl = s;
#pragma unroll
  for (int off = 1; off < 64; off <<= 1) {
    int t = __shfl_up(incl, off);
    if (lane >= off) incl += t;
  }
  __shared__ int wsum[4];
  if (lane == 63) wsum[tid >> 6] = incl;
  __syncthreads();
  int woff = 0;
  int w = tid >> 6;
  for (int k = 0; k < 4; ++k)
    if (k < w) woff += wsum[k];
  int run = incl - s + woff + bsum[blockIdx.y * nb + blockIdx.x];
#pragma unroll
  for (int j = 0; j < 8; ++j) {
    int i = e0 + j;
    if (i <= n) row[i] = run;
    run += v[j];
  }
}

__global__ __launch_bounds__(256) void cursor_kernel(
    int* __restrict__ Hd, int* __restrict__ Hs,
    const int* __restrict__ row_d, const int* __restrict__ row_s, int N) {
  int n = blockIdx.x * 256 + threadIdx.x;
  if (n >= N) return;
  int rd = row_d[n], rs = row_s[n];
#pragma unroll
  for (int c = 0; c < NCHK; ++c) {
    int t = Hd[(size_t)c * N + n]; Hd[(size_t)c * N + n] = rd; rd += t;
    t = Hs[(size_t)c * N + n];     Hs[(size_t)c * N + n] = rs; rs += t;
  }
}

__global__ __launch_bounds__(256) void scatter_kernel(
    const int* __restrict__ src, const int* __restrict__ dst,
    const int* __restrict__ Hd, const int* __restrict__ Hs,
    int* __restrict__ col_d, int* __restrict__ col_s, int E, int N, int chunk) {
  int g = blockIdx.x, c = blockIdx.y, z = blockIdx.z;
  const int* key = z ? src : dst;
  const int* val = z ? dst : src;
  const int* H = z ? Hs : Hd;
  int* colp = z ? col_s : col_d;
  int lo = (int)((long long)N * g / NGRP);
  int hi = (int)((long long)N * (g + 1) / NGRP);
  int range = hi - lo;
  __shared__ int cur[RMAX];
  for (int i = threadIdx.x; i < range; i += 256)
    cur[i] = H[(size_t)c * N + lo + i];
  __syncthreads();
  int e0 = c * chunk, e1 = min(E, e0 + chunk);
  for (int e = e0 + (int)threadIdx.x * 4; e < e1; e += 1024) {
    if (e + 4 <= e1) {
      int4 k4 = *(const int4*)(key + e);
      int4 v4 = *(const int4*)(val + e);
      if (k4.x >= lo && k4.x < hi) { int p = atomicAdd(&cur[k4.x - lo], 1); colp[p] = v4.x; }
      if (k4.y >= lo && k4.y < hi) { int p = atomicAdd(&cur[k4.y - lo], 1); colp[p] = v4.y; }
      if (k4.z >= lo && k4.z < hi) { int p = atomicAdd(&cur[k4.z - lo], 1); colp[p] = v4.z; }
      if (k4.w >= lo && k4.w < hi) { int p = atomicAdd(&cur[k4.w - lo], 1); colp[p] = v4.w; }
    } else {
      for (int k = e; k < e1; ++k) {
        int kk = key[k], vv = val[k];
        if (kk >= lo && kk < hi) { int p = atomicAdd(&cur[kk - lo], 1); colp[p] = vv; }
      }
    }
  }
}

// ---------------- aggregation: split tables, XCD-half-split, 8 nodes/wave ----------
// blockIdx.x bit0 = fh selects the PHYSICAL half-table (64B rows, no shared
// L2 lines). XCD id = linear%8 -> even XCDs gather only Lo (3.2 MB < 4 MB L2),
// odd only Hi. Lane: g=lane>>3 node slot, fl=lane&7 -> 4 features (uint2).
// Degree divergence branch-free: 0/1 FMA weight, clamped col index.

__global__ __launch_bounds__(256) void aggs_kernel(
    const ushort* __restrict__ hLo, const ushort* __restrict__ hHi,
    const int* __restrict__ row_d, const int* __restrict__ col_d,
    ushort* __restrict__ g1Lo, ushort* __restrict__ g1Hi,
    const int* __restrict__ row_s, const int* __restrict__ col_s,
    ushort* __restrict__ g2Lo, ushort* __restrict__ g2Hi,
    int N, int E) {
  int b = blockIdx.x;
  int fh = b & 1;
  int rest = b >> 1;
  int dir = rest & 1;
  int wvblk = rest >> 1;
  const int* row = dir ? row_s : row_d;
  const int* col = dir ? col_s : col_d;
  const ushort* tbl = fh ? hHi : hLo;
  ushort* outp = dir ? (fh ? g2Hi : g2Lo) : (fh ? g1Hi : g1Lo);
  int lane = threadIdx.x & 63;
  int g = lane >> 3;
  int fl = lane & 7;
  int node = (wvblk * 4 + (threadIdx.x >> 6)) * 8 + g;
  int nc = min(node, N - 1);
  int s0 = row[nc], s1 = row[nc + 1];
  int d = s1 - s0;
  int dmax = d;
  dmax = max(dmax, __shfl_xor(dmax, 8));
  dmax = max(dmax, __shfl_xor(dmax, 16));
  dmax = max(dmax, __shfl_xor(dmax, 32));
  const ushort* tab = tbl + fl * 4;
  float a0 = 0.f, a1 = 0.f, a2 = 0.f, a3 = 0.f;
  float b0 = 0.f, b1 = 0.f, b2 = 0.f, b3 = 0.f;
  int i = 0;
  for (; i + 2 <= dmax; i += 2) {
    int p0 = s0 + i, p1 = p0 + 1;
    float w0 = p0 < s1 ? 1.f : 0.f;
    float w1 = p1 < s1 ? 1.f : 0.f;
    int n0 = col[min(p0, E - 1)];
    int n1 = col[min(p1, E - 1)];
    uint2 u0 = *(const uint2*)(tab + (size_t)n0 * HDIM);
    uint2 u1 = *(const uint2*)(tab + (size_t)n1 * HDIM);
    a0 += w0 * bflo(u0.x); a1 += w0 * bfhi(u0.x);
    a2 += w0 * bflo(u0.y); a3 += w0 * bfhi(u0.y);
    b0 += w1 * bflo(u1.x); b1 += w1 * bfhi(u1.x);
    b2 += w1 * bflo(u1.y); b3 += w1 * bfhi(u1.y);
  }
  if (i < dmax) {
    int p = s0 + i;
    float w = p < s1 ? 1.f : 0.f;
    int n = col[min(p, E - 1)];
    uint2 u = *(const uint2*)(tab + (size_t)n * HDIM);
    a0 += w * bflo(u.x); a1 += w * bfhi(u.x);
    a2 += w * bflo(u.y); a3 += w * bfhi(u.y);
  }
  a0 += b0; a1 += b1; a2 += b2; a3 += b3;
  float inv = d > 0 ? 1.f / (float)d : 0.f;
  if (node < N) {
    uint2 o;
    o.x = f2bf2(a0 * inv, a1 * inv);
    o.y = f2bf2(a2 * inv, a3 * inv);
    *(uint2*)(outp + (size_t)node * HDIM + fl * 4) = o;
  }
}

// ---------------- combine: 128-node bf16 LDS tile from split tables ----------------
// 2 nodes/lane, wave=16 outputs; fp32 weights/acc. Staging thread (r,hf) loads
// the full 64B half-row (4 x uint4) of node r from the hf table.

__global__ __launch_bounds__(256, 3) void combine_kernel(
    const ushort* __restrict__ hLo, const ushort* __restrict__ hHi,
    const ushort* __restrict__ g1Lo, const ushort* __restrict__ g1Hi,
    const ushort* __restrict__ g2Lo, const ushort* __restrict__ g2Hi,
    const float* __restrict__ wrT, const float* __restrict__ w1T,
    const float* __restrict__ w2T, const float* __restrict__ bias,
    ushort* __restrict__ outLo, ushort* __restrict__ outHi, int N) {
  __shared__ uint Ht[128][33];
  __shared__ uint G1t[128][33];
  __shared__ uint G2t[128][33];
  int tid = threadIdx.x;
  int n0 = blockIdx.x * 128;
  {
    int r = tid >> 1, hf = tid & 1;
    int nc = min(n0 + r, N - 1);
    const uint4* ph = (const uint4*)((hf ? hHi : hLo) + (size_t)nc * HDIM);
    const uint4* p1 = (const uint4*)((hf ? g1Hi : g1Lo) + (size_t)nc * HDIM);
    const uint4* p2 = (const uint4*)((hf ? g2Hi : g2Lo) + (size_t)nc * HDIM);
#pragma unroll
    for (int i = 0; i < 4; ++i) {
      uint4 a = ph[i], b = p1[i], c = p2[i];
      int base = hf * 16 + i * 4;
      Ht[r][base+0]=a.x;  Ht[r][base+1]=a.y;  Ht[r][base+2]=a.z;  Ht[r][base+3]=a.w;
      G1t[r][base+0]=b.x; G1t[r][base+1]=b.y; G1t[r][base+2]=b.z; G1t[r][base+3]=b.w;
      G2t[r][base+0]=c.x; G2t[r][base+1]=c.y; G2t[r][base+2]=c.z; G2t[r][base+3]=c.w;
    }
  }
  __syncthreads();
  int w = __builtin_amdgcn_readfirstlane(tid >> 6);
  int lane = tid & 63;
  int ob = w * 16;
  float aa[16], ab[16];
#pragma unroll
  for (int o = 0; o < 16; ++o) { float bv = bias[ob + o]; aa[o] = bv; ab[o] = bv; }
  for (int kp = 0; kp < 32; ++kp) {
    uint hua = Ht[lane][kp],  hub = Ht[lane + 64][kp];
    uint gua = G1t[lane][kp], gub = G1t[lane + 64][kp];
    uint fua = G2t[lane][kp], fub = G2t[lane + 64][kp];
    float ha0 = bflo(hua), ha1 = bfhi(hua), hb0 = bflo(hub), hb1 = bfhi(hub);
    float ga0 = bflo(gua), ga1 = bfhi(gua), gb0 = bflo(gub), gb1 = bfhi(gub);
    float fa0 = bflo(fua), fa1 = bfhi(fua), fb0 = bflo(fub), fb1 = bfhi(fub);
    const float4* pa0 = (const float4*)(wrT + (2 * kp) * 64 + ob);
    const float4* pa1 = (const float4*)(wrT + (2 * kp + 1) * 64 + ob);
    const float4* pb0 = (const float4*)(w1T + (2 * kp) * 64 + ob);
    const float4* pb1 = (const float4*)(w1T + (2 * kp + 1) * 64 + ob);
    const float4* pc0 = (const float4*)(w2T + (2 * kp) * 64 + ob);
    const float4* pc1 = (const float4*)(w2T + (2 * kp + 1) * 64 + ob);
#pragma unroll
    for (int j = 0; j < 4; ++j) {
      float4 A0 = pa0[j], A1 = pa1[j];
      float4 B0 = pb0[j], B1 = pb1[j];
      float4 C0 = pc0[j], C1 = pc1[j];
      aa[4*j+0] += ha0*A0.x + ha1*A1.x + ga0*B0.x + ga1*B1.x + fa0*C0.x + fa1*C1.x;
      aa[4*j+1] += ha0*A0.y + ha1*A1.y + ga0*B0.y + ga1*B1.y + fa0*C0.y + fa1*C1.y;
      aa[4*j+2] += ha0*A0.z + ha1*A1.z + ga0*B0.z + ga1*B1.z + fa0*C0.z + fa1*C1.z;
      aa[4*j+3] += ha0*A0.w + ha1*A1.w + ga0*B0.w + ga1*B1.w + fa0*C0.w + fa1*C1.w;
      ab[4*j+0] += hb0*A0.x + hb1*A1.x + gb0*B0.x + gb1*B1.x + fb0*C0.x + fb1*C1.x;
      ab[4*j+1] += hb0*A0.y + hb1*A1.y + gb0*B0.y + gb1*B1.y + fb0*C0.y + fb1*C1.y;
      ab[4*j+2] += hb0*A0.z + hb1*A1.z + gb0*B0.z + gb1*B1.z + fb0*C0.z + fb1*C1.z;
      ab[4*j+3] += hb0*A0.w + hb1*A1.w + gb0*B0.w + gb1*B1.w + fb0*C0.w + fb1*C1.w;
    }
  }
  ushort* tbl = (w >= 2) ? outHi : outLo;
  int off = (w & 1) * 16;            // ushort offset within 32-elem half-row
  int na = n0 + lane, nb = n0 + 64 + lane;
  if (na < N) {
    uint4 u0, u1;
    u0.x = f2bf2(fmaxf(aa[0],0.f),  fmaxf(aa[1],0.f));
    u0.y = f2bf2(fmaxf(aa[2],0.f),  fmaxf(aa[3],0.f));
    u0.z = f2bf2(fmaxf(aa[4],0.f),  fmaxf(aa[5],0.f));
    u0.w = f2bf2(fmaxf(aa[6],0.f),  fmaxf(aa[7],0.f));
    u1.x = f2bf2(fmaxf(aa[8],0.f),  fmaxf(aa[9],0.f));
    u1.y = f2bf2(fmaxf(aa[10],0.f), fmaxf(aa[11],0.f));
    u1.z = f2bf2(fmaxf(aa[12],0.f), fmaxf(aa[13],0.f));
    u1.w = f2bf2(fmaxf(aa[14],0.f), fmaxf(aa[15],0.f));
    uint4* op = (uint4*)(tbl + (size_t)na * HDIM + off);
    op[0] = u0; op[1] = u1;
  }
  if (nb < N) {
    uint4 u0, u1;
    u0.x = f2bf2(fmaxf(ab[0],0.f),  fmaxf(ab[1],0.f));
    u0.y = f2bf2(fmaxf(ab[2],0.f),  fmaxf(ab[3],0.f));
    u0.z = f2bf2(fmaxf(ab[4],0.f),  fmaxf(ab[5],0.f));
    u0.w = f2bf2(fmaxf(ab[6],0.f),  fmaxf(ab[7],0.f));
    u1.x = f2bf2(fmaxf(ab[8],0.f),  fmaxf(ab[9],0.f));
    u1.y = f2bf2(fmaxf(ab[10],0.f), fmaxf(ab[11],0.f));
    u1.z = f2bf2(fmaxf(ab[12],0.f), fmaxf(ab[13],0.f));
    u1.w = f2bf2(fmaxf(ab[14],0.f), fmaxf(ab[15],0.f));
    uint4* op = (uint4*)(tbl + (size_t)nb * HDIM + off);
    op[0] = u0; op[1] = u1;
  }
}

// ---------------- final: 128-node bf16 LDS tiles (4 split bufs), 2 nodes/lane ----------

__global__ __launch_bounds__(256, 2) void final_kernel(
    const ushort* __restrict__ x0, const ushort* __restrict__ x1,
    const ushort* __restrict__ h10, const ushort* __restrict__ h11,
    const ushort* __restrict__ h20, const ushort* __restrict__ h21,
    const ushort* __restrict__ h30, const ushort* __restrict__ h31,
    const float* __restrict__ fwT, const float* __restrict__ fb,
    float* __restrict__ outp, int N) {
  __shared__ uint Ft[4][128][33];
  int tid = threadIdx.x;
  int n0 = blockIdx.x * 128;
  {
    int r = tid >> 1, hf = tid & 1;
    int nc = min(n0 + r, N - 1);
    const ushort* bufs[4][2] = {{x0, x1}, {h10, h11}, {h20, h21}, {h30, h31}};
#pragma unroll
    for (int b = 0; b < 4; ++b) {
      const uint4* ip = (const uint4*)(bufs[b][hf] + (size_t)nc * HDIM);
#pragma unroll
      for (int i = 0; i < 4; ++i) {
        uint4 v = ip[i];
        int base = hf * 16 + i * 4;
        Ft[b][r][base+0]=v.x; Ft[b][r][base+1]=v.y;
        Ft[b][r][base+2]=v.z; Ft[b][r][base+3]=v.w;
      }
    }
  }
  __syncthreads();
  int w = __builtin_amdgcn_readfirstlane(tid >> 6);
  int lane = tid & 63;
  int ob = w * 16;
  float aa[16], ab[16];
#pragma unroll
  for (int o = 0; o < 16; ++o) { float bv = fb[ob + o]; aa[o] = bv; ab[o] = bv; }
  for (int kp = 0; kp < 128; ++kp) {
    int buf = kp >> 5, kk = kp & 31;
    uint ua = Ft[buf][lane][kk], ub = Ft[buf][lane + 64][kk];
    float a0 = bflo(ua), a1 = bfhi(ua), b0 = bflo(ub), b1 = bfhi(ub);
    const float4* p0 = (const float4*)(fwT + (2 * kp) * 64 + ob);
    const float4* p1 = (const float4*)(fwT + (2 * kp + 1) * 64 + ob);
#pragma unroll
    for (int j = 0; j < 4; ++j) {
      float4 W0 = p0[j], W1 = p1[j];
      aa[4*j+0] += a0*W0.x + a1*W1.x;
      aa[4*j+1] += a0*W0.y + a1*W1.y;
      aa[4*j+2] += a0*W0.z + a1*W1.z;
      aa[4*j+3] += a0*W0.w + a1*W1.w;
      ab[4*j+0] += b0*W0.x + b1*W1.x;
      ab[4*j+1] += b0*W0.y + b1*W1.y;
      ab[4*j+2] += b0*W0.z + b1*W1.z;
      ab[4*j+3] += b0*W0.w + b1*W1.w;
    }
  }
  int na = n0 + lane, nb = n0 + 64 + lane;
  if (na < N) {
    float4* op = (float4*)(outp + (size_t)na * NDIM + ob);
#pragma unroll
    for (int j = 0; j < 4; ++j) {
      float4 v; v.x = aa[4*j+0]; v.y = aa[4*j+1]; v.z = aa[4*j+2]; v.w = aa[4*j+3];
      op[j] = v;
    }
  }
  if (nb < N) {
    float4* op = (float4*)(outp + (size_t)nb * NDIM + ob);
#pragma unroll
    for (int j = 0; j < 4; ++j) {
      float4 v; v.x = ab[4*j+0]; v.y = ab[4*j+1]; v.z = ab[4*j+2]; v.w = ab[4*j+3];
      op[j] = v;
    }
  }
}

// ---------------- launch ----------------

extern "C" void kernel_launch(void* const* d_in, const int* in_sizes, int n_in,
                              void* d_out, int out_size, void* d_ws, size_t ws_size,
                              hipStream_t stream) {
  const float* x     = (const float*)d_in[0];
  const int*   ei    = (const int*)d_in[1];
  const float* lin1  = (const float*)d_in[2];
  const float* lin2  = (const float*)d_in[3];
  const float* rootw = (const float*)d_in[4];
  const float* rootb = (const float*)d_in[5];
  const float* fw    = (const float*)d_in[6];
  const float* fb    = (const float*)d_in[7];
  float* out = (float*)d_out;

  int N = in_sizes[0] / NDIM;
  int E = in_sizes[1] / 2;
  const int* src = ei;
  const int* dst = ei + E;

  int* ip = (int*)d_ws;
  int* Hd    = ip; ip += (size_t)NCHK * N;
  int* Hs    = ip; ip += (size_t)NCHK * N;
  int* deg_d = ip; ip += N;
  int* deg_s = ip; ip += N;
  int* row_d = ip; ip += N + 1;
  int* row_s = ip; ip += N + 1;
  int* bsum  = ip; ip += 256;
  int* col_d = ip; ip += E;
  int* col_s = ip; ip += E;
  uintptr_t fbase = (((uintptr_t)ip) + 255) & ~(uintptr_t)255;
  float* fwT = (float*)fbase;
  float* wrT = fwT + 16384;
  float* w1T = wrT + 12288;
  float* w2T = w1T + 12288;
  // split bf16 tables: 4 activations x {Lo,Hi} + g1/g2 x {Lo,Hi}
  ushort* tb = (ushort*)(w2T + 12288);
  size_t HT = (size_t)N * HDIM;
  ushort* hT[4][2];
  for (int l = 0; l < 4; ++l)
    for (int h = 0; h < 2; ++h) { hT[l][h] = tb; tb += HT; }
  ushort* g1Lo = tb; tb += HT;
  ushort* g1Hi = tb; tb += HT;
  ushort* g2Lo = tb; tb += HT;
  ushort* g2Hi = tb; tb += HT;

  int chunk = (E + NCHK - 1) / NCHK;
  int nb = (N + SCAN_ELEMS - 1) / SCAN_ELEMS;
  int nblk = (N + 255) / 256;

  transpose_kernel<<<112, 256, 0, stream>>>(fw, rootw, lin1, lin2, fwT, wrT, w1T, w2T);
  convx_kernel<<<(N * 16 + 255) / 256, 256, 0, stream>>>(x, hT[0][0], hT[0][1], N * 16);
  hist_kernel<<<dim3(NCHK, NGRP, 2), 256, 0, stream>>>(src, dst, Hd, Hs, E, N, chunk);
  degsum_kernel<<<nblk, 256, 0, stream>>>(Hd, Hs, deg_d, deg_s, N);
  scan_partial<<<dim3(nb, 2), 256, 0, stream>>>(deg_d, deg_s, bsum, N, nb);
  scan_bsum<<<1, 256, 0, stream>>>(bsum, nb);
  scan_final<<<dim3(nb, 2), 256, 0, stream>>>(deg_d, deg_s, bsum, row_d, row_s, N, nb);
  cursor_kernel<<<nblk, 256, 0, stream>>>(Hd, Hs, row_d, row_s, N);
  scatter_kernel<<<dim3(NGRP, NCHK, 2), 256, 0, stream>>>(src, dst, Hd, Hs,
                                                          col_d, col_s, E, N, chunk);

  int nwb = (N + 31) / 32;          // node blocks (4 waves x 8 nodes)
  int asgrid = nwb * 4;             // bit0=fh, bit1=dir, rest=node block
  int tgrid = (N + 127) / 128;
  for (int l = 0; l < 3; ++l) {
    aggs_kernel<<<asgrid, 256, 0, stream>>>(hT[l][0], hT[l][1],
                                            row_d, col_d, g1Lo, g1Hi,
                                            row_s, col_s, g2Lo, g2Hi, N, E);
    combine_kernel<<<tgrid, 256, 0, stream>>>(hT[l][0], hT[l][1],
                                              g1Lo, g1Hi, g2Lo, g2Hi,
                                              wrT + (size_t)l * 4096,
                                              w1T + (size_t)l * 4096,
                                              w2T + (size_t)l * 4096,
                                              rootb + (size_t)l * 64,
                                              hT[l + 1][0], hT[l + 1][1], N);
  }
  final_kernel<<<tgrid, 256, 0, stream>>>(hT[0][0], hT[0][1], hT[1][0], hT[1][1],
                                          hT[2][0], hT[2][1], hT[3][0], hT[3][1],
                                          fwT, fb, out, N);
}